// Round 4
// baseline (3367.287 us; speedup 1.0000x reference)
//
#include <hip/hip_runtime.h>
#include <math.h>

#define H 32
#define BSEG 16
#define CHUNKS 32

__device__ __forceinline__ float sigmoidf_(float x){ return 1.f/(1.f+expf(-x)); }

// ---------------- prep: transposed GRU weights, fused biases, qvec, zero accumulators ----------------
// WI[k*1024 + i*32 + o] = gru_wi[(k*32+o)*32 + i]   (gi_k[o] = sum_i out[i]*WI_k[i][o])
// WH likewise from gru_wh.
// BS[0..31]=bi0+bh0, [32..63]=bi1+bh1, [64..95]=bi2, [96..127]=bh2
__global__ __launch_bounds__(512) void k_prep(
    const float* __restrict__ gru_wi, const float* __restrict__ gru_wh,
    const float* __restrict__ gru_bi, const float* __restrict__ gru_bh,
    const float* __restrict__ lstm_bi, const float* __restrict__ lstm_bh,
    float* __restrict__ WI, float* __restrict__ WH, float* __restrict__ BS,
    float* __restrict__ qvec, unsigned int* __restrict__ segmax,
    float* __restrict__ ssum, float* __restrict__ vsum)
{
    int t = threadIdx.x;
    for (int idx = t; idx < 3072; idx += 512) {
        int k = idx >> 10, rem = idx & 1023, i = rem >> 5, o = rem & 31;
        WI[idx] = gru_wi[(k*32 + o)*32 + i];
        WH[idx] = gru_wh[(k*32 + o)*32 + i];
    }
    if (t < 32) {
        BS[t]      = gru_bi[t]      + gru_bh[t];
        BS[32 + t] = gru_bi[32 + t] + gru_bh[32 + t];
        BS[64 + t] = gru_bi[64 + t];
        BS[96 + t] = gru_bh[64 + t];
    }
    if (t < H) {
        float g0 = lstm_bi[t] + lstm_bh[t];
        float g2 = lstm_bi[2*H + t] + lstm_bh[2*H + t];
        float g3 = lstm_bi[3*H + t] + lstm_bh[3*H + t];
        float ig = sigmoidf_(g0);
        float gg = tanhf(g2);
        float og = sigmoidf_(g3);
        qvec[t] = og * tanhf(ig * gg);
    }
    for (int i = t; i < BSEG; i += 512) { segmax[i] = 0u; ssum[i] = 0.f; }
    for (int i = t; i < BSEG*H; i += 512) vsum[i] = 0.f;
}

// ---------------- proj: h = relu(x @ proj_w + proj_b); agg = 0. One node per lane. ----------------
__global__ __launch_bounds__(256) void k_proj(
    const float* __restrict__ x, const float* __restrict__ proj_w, const float* __restrict__ proj_b,
    float* __restrict__ h, float* __restrict__ agg, int N)
{
    int n = blockIdx.x * 256 + threadIdx.x;
    if (n >= N) return;
    float4 xv = *(const float4*)&x[n * 4];
    #pragma unroll
    for (int q = 0; q < 8; ++q) {
        float r_[4];
        #pragma unroll
        for (int j = 0; j < 4; ++j) {
            int o = q*4 + j;
            float a = proj_b[o];
            a = fmaf(xv.x, proj_w[0*32 + o], a);
            a = fmaf(xv.y, proj_w[1*32 + o], a);
            a = fmaf(xv.z, proj_w[2*32 + o], a);
            a = fmaf(xv.w, proj_w[3*32 + o], a);
            r_[j] = fmaxf(a, 0.f);
        }
        *(float4*)&h[n*32 + q*4]   = make_float4(r_[0], r_[1], r_[2], r_[3]);
        *(float4*)&agg[n*32 + q*4] = make_float4(0.f, 0.f, 0.f, 0.f);
    }
}

// ---------------- G: G[n, c*32+o] = sum_i h[n,i] * Wc[i][o]. One node per lane, chunk = blockIdx.y ----------------
__global__ __launch_bounds__(256) void k_G(
    const float* __restrict__ h, const float* __restrict__ e2w, const float* __restrict__ e2b,
    float* __restrict__ G, int N)
{
    int n = blockIdx.x * 256 + threadIdx.x;
    int c = blockIdx.y;
    if (n >= N) return;
    const float* __restrict__ Wc = (c < 8) ? (e2w + c * 1024) : e2b;
    float hreg[32];
    #pragma unroll
    for (int q = 0; q < 8; ++q) {
        float4 v = *(const float4*)&h[n*32 + q*4];
        hreg[q*4+0] = v.x; hreg[q*4+1] = v.y; hreg[q*4+2] = v.z; hreg[q*4+3] = v.w;
    }
    float acc[32];
    #pragma unroll
    for (int o = 0; o < 32; ++o) acc[o] = 0.f;
    #pragma unroll
    for (int i = 0; i < 32; ++i) {
        float hv = hreg[i];
        #pragma unroll
        for (int o = 0; o < 32; ++o) acc[o] = fmaf(hv, Wc[i*32 + o], acc[o]);
    }
    float* Gp = G + (size_t)n * 288 + c * 32;
    #pragma unroll
    for (int q = 0; q < 8; ++q)
        *(float4*)&Gp[q*4] = make_float4(acc[q*4+0], acc[q*4+1], acc[q*4+2], acc[q*4+3]);
}

// ---------------- GRU node update: one node per lane, all in registers, weights via SGPR ----------------
__global__ __launch_bounds__(256) void k_gru(
    float* __restrict__ h, float* __restrict__ agg,
    const float* __restrict__ root_w, const float* __restrict__ conv_b,
    const float* __restrict__ WI, const float* __restrict__ WH, const float* __restrict__ BS,
    int N)
{
    int n = blockIdx.x * 256 + threadIdx.x;
    if (n >= N) return;
    float hreg[32];
    #pragma unroll
    for (int q = 0; q < 8; ++q) {
        float4 v = *(const float4*)&h[n*32 + q*4];
        hreg[q*4+0] = v.x; hreg[q*4+1] = v.y; hreg[q*4+2] = v.z; hreg[q*4+3] = v.w;
    }
    // out = relu(agg + h@root_w + conv_b); re-zero agg
    float out[32];
    #pragma unroll
    for (int q = 0; q < 8; ++q) {
        float4 v = *(const float4*)&agg[n*32 + q*4];
        out[q*4+0] = v.x + conv_b[q*4+0];
        out[q*4+1] = v.y + conv_b[q*4+1];
        out[q*4+2] = v.z + conv_b[q*4+2];
        out[q*4+3] = v.w + conv_b[q*4+3];
        *(float4*)&agg[n*32 + q*4] = make_float4(0.f, 0.f, 0.f, 0.f);
    }
    #pragma unroll
    for (int i = 0; i < 32; ++i) {
        float hv = hreg[i];
        #pragma unroll
        for (int o = 0; o < 32; ++o) out[o] = fmaf(hv, root_w[i*32 + o], out[o]);
    }
    #pragma unroll
    for (int o = 0; o < 32; ++o) out[o] = fmaxf(out[o], 0.f);

    // r = sigmoid(out@WI0 + h@WH0 + bs0)
    float r[32];
    #pragma unroll
    for (int o = 0; o < 32; ++o) r[o] = BS[o];
    #pragma unroll
    for (int i = 0; i < 32; ++i) {
        float ov = out[i], hv = hreg[i];
        #pragma unroll
        for (int o = 0; o < 32; ++o)
            r[o] = fmaf(ov, WI[i*32 + o], fmaf(hv, WH[i*32 + o], r[o]));
    }
    #pragma unroll
    for (int o = 0; o < 32; ++o) r[o] = sigmoidf_(r[o]);

    // gh2 = h@WH2 + bh2, then fold r in immediately (frees r)
    float gh2[32];
    #pragma unroll
    for (int o = 0; o < 32; ++o) gh2[o] = BS[96 + o];
    #pragma unroll
    for (int i = 0; i < 32; ++i) {
        float hv = hreg[i];
        #pragma unroll
        for (int o = 0; o < 32; ++o) gh2[o] = fmaf(hv, WH[2048 + i*32 + o], gh2[o]);
    }
    #pragma unroll
    for (int o = 0; o < 32; ++o) gh2[o] *= r[o];

    // z = sigmoid(out@WI1 + h@WH1 + bs1)
    float z[32];
    #pragma unroll
    for (int o = 0; o < 32; ++o) z[o] = BS[32 + o];
    #pragma unroll
    for (int i = 0; i < 32; ++i) {
        float ov = out[i], hv = hreg[i];
        #pragma unroll
        for (int o = 0; o < 32; ++o)
            z[o] = fmaf(ov, WI[1024 + i*32 + o], fmaf(hv, WH[1024 + i*32 + o], z[o]));
    }
    #pragma unroll
    for (int o = 0; o < 32; ++o) z[o] = sigmoidf_(z[o]);

    // gi2 = out@WI2 + bi2; n = tanh(gi2 + r*gh2); hnew = (1-z)*n + z*h
    float acc[32];
    #pragma unroll
    for (int o = 0; o < 32; ++o) acc[o] = BS[64 + o];
    #pragma unroll
    for (int i = 0; i < 32; ++i) {
        float ov = out[i];
        #pragma unroll
        for (int o = 0; o < 32; ++o) acc[o] = fmaf(ov, WI[2048 + i*32 + o], acc[o]);
    }
    #pragma unroll
    for (int o = 0; o < 32; ++o) {
        float nv = tanhf(acc[o] + gh2[o]);
        hreg[o] = (1.f - z[o]) * nv + z[o] * hreg[o];
    }
    #pragma unroll
    for (int q = 0; q < 8; ++q)
        *(float4*)&h[n*32 + q*4] = make_float4(hreg[q*4+0], hreg[q*4+1], hreg[q*4+2], hreg[q*4+3]);
}

// ---------------- edges: m[e,o] = sum_k t_k G[src,k,o] + G[src,8,o]; atomic agg[dst] ----------------
__global__ __launch_bounds__(256) void k_edge(
    const int* __restrict__ ei, const float* __restrict__ ea,
    const float* __restrict__ e1w, const float* __restrict__ e1b,
    const float* __restrict__ G, float* __restrict__ agg, int E)
{
    int tid = blockIdx.x * 256 + threadIdx.x;
    int e = tid >> 5;
    int o = tid & 31;
    if (e >= E) return;
    int src = ei[e];
    int dst = ei[E + e];
    float a = ea[e];
    const float* Gp = G + (size_t)src * 288;
    float m = Gp[8 * H + o];
    #pragma unroll
    for (int k = 0; k < 8; ++k) {
        float t = fmaxf(a * e1w[k] + e1b[k], 0.f);
        m += t * Gp[k * H + o];
    }
    atomicAdd(&agg[dst * H + o], m);
}

__device__ __forceinline__ unsigned int fenc(float f) {
    int i = __float_as_int(f);
    return (i >= 0) ? ((unsigned int)i | 0x80000000u) : ~(unsigned int)i;
}
__device__ __forceinline__ float fdec(unsigned int u) {
    int i = (u & 0x80000000u) ? (int)(u & 0x7FFFFFFFu) : (int)(~u);
    return __int_as_float(i);
}

// ---------------- readout pass1: e[n] = h[n]·q, segment max ----------------
__global__ __launch_bounds__(256) void k_pass1(
    const float* __restrict__ h, const int* __restrict__ batch,
    const float* __restrict__ qvec, float* __restrict__ ebuf,
    unsigned int* __restrict__ segmax, int N)
{
    int b = blockIdx.x / CHUNKS;
    int c = blockIdx.x % CHUNKS;
    int lo = 0, hi = N;
    while (lo < hi) { int mid = (lo + hi) >> 1; if (batch[mid] < b) lo = mid + 1; else hi = mid; }
    int s = lo;
    lo = 0; hi = N;
    while (lo < hi) { int mid = (lo + hi) >> 1; if (batch[mid] < b + 1) lo = mid + 1; else hi = mid; }
    int e = lo;
    int len = e - s;
    int per = (len + CHUNKS - 1) / CHUNKS;
    int n0 = s + c * per;
    int n1 = min(n0 + per, e);

    int tid = threadIdx.x;
    int ln = tid >> 5, o = tid & 31;
    float qv = qvec[o];
    float mloc = -INFINITY;
    for (int nn = n0 + ln; nn < n1; nn += 8) {
        float v = h[nn * H + o] * qv;
        #pragma unroll
        for (int m = 16; m >= 1; m >>= 1) v += __shfl_xor(v, m);
        if (o == 0) ebuf[nn] = v;
        mloc = fmaxf(mloc, v);
    }
    __shared__ float red[256];
    red[tid] = mloc;
    __syncthreads();
    for (int st = 128; st >= 1; st >>= 1) {
        if (tid < st) red[tid] = fmaxf(red[tid], red[tid + st]);
        __syncthreads();
    }
    if (tid == 0 && n0 < n1) atomicMax(&segmax[b], fenc(red[0]));
}

// ---------------- readout pass2: a = exp(e - emax); vsum += a*h; ssum += a ----------------
__global__ __launch_bounds__(256) void k_pass2(
    const float* __restrict__ h, const int* __restrict__ batch,
    const float* __restrict__ ebuf, const unsigned int* __restrict__ segmax,
    float* __restrict__ ssum, float* __restrict__ vsum, int N)
{
    int b = blockIdx.x / CHUNKS;
    int c = blockIdx.x % CHUNKS;
    int lo = 0, hi = N;
    while (lo < hi) { int mid = (lo + hi) >> 1; if (batch[mid] < b) lo = mid + 1; else hi = mid; }
    int s = lo;
    lo = 0; hi = N;
    while (lo < hi) { int mid = (lo + hi) >> 1; if (batch[mid] < b + 1) lo = mid + 1; else hi = mid; }
    int e = lo;
    int len = e - s;
    int per = (len + CHUNKS - 1) / CHUNKS;
    int n0 = s + c * per;
    int n1 = min(n0 + per, e);

    int tid = threadIdx.x;
    int ln = tid >> 5, o = tid & 31;
    float emax = fdec(segmax[b]);
    float vacc = 0.f, sacc = 0.f;
    for (int nn = n0 + ln; nn < n1; nn += 8) {
        float a = expf(ebuf[nn] - emax);
        vacc += a * h[nn * H + o];
        if (o == 0) sacc += a;
    }
    __shared__ float vsh[8][H];
    __shared__ float ssh[8];
    vsh[ln][o] = vacc;
    if (o == 0) ssh[ln] = sacc;
    __syncthreads();
    if (tid < H) {
        float v = 0.f;
        #pragma unroll
        for (int g = 0; g < 8; ++g) v += vsh[g][tid];
        atomicAdd(&vsum[b * H + tid], v);
    } else if (tid == H) {
        float stot = 0.f;
        #pragma unroll
        for (int g = 0; g < 8; ++g) stot += ssh[g];
        atomicAdd(&ssum[b], stot);
    }
}

// ---------------- final MLP on (16, 64) ----------------
__global__ __launch_bounds__(512) void k_mlp(
    const float* __restrict__ qvec, const float* __restrict__ ssum, const float* __restrict__ vsum,
    const float* __restrict__ f1w, const float* __restrict__ f1b,
    const float* __restrict__ f2w, const float* __restrict__ f2b,
    const float* __restrict__ f3w, const float* __restrict__ f3b,
    float* __restrict__ out)
{
    __shared__ float qsm[BSEG][2 * H];
    __shared__ float o1[BSEG][H];
    __shared__ float o2[BSEG][H];
    int tid = threadIdx.x;
    int b = tid >> 5, j = tid & 31;
    float st = ssum[b];
    qsm[b][j] = qvec[j];
    qsm[b][H + j] = (st > 0.f) ? vsum[b * H + j] / st : 0.f;
    __syncthreads();
    float acc = f1b[j];
    for (int i = 0; i < 2 * H; ++i) acc += qsm[b][i] * f1w[i * H + j];
    o1[b][j] = fmaxf(acc, 0.f);
    __syncthreads();
    acc = f2b[j];
    for (int i = 0; i < H; ++i) acc += o1[b][i] * f2w[i * H + j];
    o2[b][j] = fmaxf(acc, 0.f);
    __syncthreads();
    float v = o2[b][j] * f3w[j];
    #pragma unroll
    for (int m = 16; m >= 1; m >>= 1) v += __shfl_xor(v, m);
    if (j == 0) out[b] = v + f3b[0];
}

extern "C" void kernel_launch(void* const* d_in, const int* in_sizes, int n_in,
                              void* d_out, int out_size, void* d_ws, size_t ws_size,
                              hipStream_t stream)
{
    const float* x      = (const float*)d_in[0];
    const int*   ei     = (const int*)d_in[1];
    const float* ea     = (const float*)d_in[2];
    const int*   batch  = (const int*)d_in[3];
    const float* proj_w = (const float*)d_in[4];
    const float* proj_b = (const float*)d_in[5];
    const float* e1w    = (const float*)d_in[6];
    const float* e1b    = (const float*)d_in[7];
    const float* e2w    = (const float*)d_in[8];
    const float* e2b    = (const float*)d_in[9];
    const float* root_w = (const float*)d_in[10];
    const float* conv_b = (const float*)d_in[11];
    const float* gru_wi = (const float*)d_in[12];
    const float* gru_wh = (const float*)d_in[13];
    const float* gru_bi = (const float*)d_in[14];
    const float* gru_bh = (const float*)d_in[15];
    const float* lstm_bi = (const float*)d_in[18];
    const float* lstm_bh = (const float*)d_in[19];
    const float* f1w    = (const float*)d_in[20];
    const float* f1b    = (const float*)d_in[21];
    const float* f2w    = (const float*)d_in[22];
    const float* f2b    = (const float*)d_in[23];
    const float* f3w    = (const float*)d_in[24];
    const float* f3b    = (const float*)d_in[25];

    const int N = in_sizes[0] / 4;
    const int E = in_sizes[2];

    float* ws   = (float*)d_ws;
    float* h    = ws;                       // N*32
    float* G    = h + (size_t)N * H;        // N*288
    float* agg  = G + (size_t)N * 288;      // N*32
    float* ebuf = agg + (size_t)N * H;      // N
    float* qvec = ebuf + N;                 // 32
    unsigned int* segmax = (unsigned int*)(qvec + H);  // 16
    float* ssum = (float*)(segmax + BSEG);  // 16
    float* vsum = ssum + BSEG;              // 512
    float* WI   = vsum + BSEG * H;          // 3072
    float* WH   = WI + 3072;                // 3072
    float* BS   = WH + 3072;                // 128

    const int nb = (N + 255) / 256;
    const int eblocks = (E * 32 + 255) / 256;

    k_prep<<<1, 512, 0, stream>>>(gru_wi, gru_wh, gru_bi, gru_bh, lstm_bi, lstm_bh,
                                  WI, WH, BS, qvec, segmax, ssum, vsum);
    k_proj<<<nb, 256, 0, stream>>>(x, proj_w, proj_b, h, agg, N);
    k_G<<<dim3(nb, 9), 256, 0, stream>>>(h, e2w, e2b, G, N);
    for (int it = 0; it < 3; ++it) {
        k_edge<<<eblocks, 256, 0, stream>>>(ei, ea, e1w, e1b, G, agg, E);
        k_gru<<<nb, 256, 0, stream>>>(h, agg, root_w, conv_b, WI, WH, BS, N);
        if (it < 2) k_G<<<dim3(nb, 9), 256, 0, stream>>>(h, e2w, e2b, G, N);
    }
    k_pass1<<<BSEG * CHUNKS, 256, 0, stream>>>(h, batch, qvec, ebuf, segmax, N);
    k_pass2<<<BSEG * CHUNKS, 256, 0, stream>>>(h, batch, ebuf, segmax, ssum, vsum, N);
    k_mlp<<<1, 512, 0, stream>>>(qvec, ssum, vsum, f1w, f1b, f2w, f2b, f3w, f3b, (float*)d_out);
}

// Round 5
// 1182.044 us; speedup vs baseline: 2.8487x; 2.8487x over previous
//
#include <hip/hip_runtime.h>
#include <math.h>

#define H 32
#define BSEG 16
#define CHUNKS 32

__device__ __forceinline__ float sigmoidf_(float x){ return 1.f/(1.f+expf(-x)); }

// ---------------- prep: transposed GRU weights, fused biases, qvec, zero accumulators ----------------
// WI[k*1024 + i*32 + o] = gru_wi[(k*32+o)*32 + i]
// WH[k*1024 + i*32 + o] = gru_wh[(k*32+o)*32 + i]
// BS[0..31]=bi0+bh0, [32..63]=bi1+bh1, [64..95]=bi2, [96..127]=bh2
__global__ __launch_bounds__(512) void k_prep(
    const float* __restrict__ gru_wi, const float* __restrict__ gru_wh,
    const float* __restrict__ gru_bi, const float* __restrict__ gru_bh,
    const float* __restrict__ lstm_bi, const float* __restrict__ lstm_bh,
    float* __restrict__ WI, float* __restrict__ WH, float* __restrict__ BS,
    float* __restrict__ qvec, unsigned int* __restrict__ segmax,
    float* __restrict__ ssum, float* __restrict__ vsum)
{
    int t = threadIdx.x;
    for (int idx = t; idx < 3072; idx += 512) {
        int k = idx >> 10, rem = idx & 1023, i = rem >> 5, o = rem & 31;
        WI[idx] = gru_wi[(k*32 + o)*32 + i];
        WH[idx] = gru_wh[(k*32 + o)*32 + i];
    }
    if (t < 32) {
        BS[t]      = gru_bi[t]      + gru_bh[t];
        BS[32 + t] = gru_bi[32 + t] + gru_bh[32 + t];
        BS[64 + t] = gru_bi[64 + t];
        BS[96 + t] = gru_bh[64 + t];
    }
    if (t < H) {
        float g0 = lstm_bi[t] + lstm_bh[t];
        float g2 = lstm_bi[2*H + t] + lstm_bh[2*H + t];
        float g3 = lstm_bi[3*H + t] + lstm_bh[3*H + t];
        float ig = sigmoidf_(g0);
        float gg = tanhf(g2);
        float og = sigmoidf_(g3);
        qvec[t] = og * tanhf(ig * gg);
    }
    for (int i = t; i < BSEG; i += 512) { segmax[i] = 0u; ssum[i] = 0.f; }
    for (int i = t; i < BSEG*H; i += 512) vsum[i] = 0.f;
}

// ---------------- init: h = relu(x@proj_w+proj_b); G = h@W3; agg = 0 ----------------
// 8 nodes per wave; lane = node(3b) x feature-group(3b); row sharing via __shfl.
__global__ __launch_bounds__(256) void k_init(
    const float* __restrict__ x, const float* __restrict__ proj_w, const float* __restrict__ proj_b,
    const float* __restrict__ e2w, const float* __restrict__ e2b,
    float* __restrict__ h, float* __restrict__ G, float* __restrict__ agg, int N)
{
    int lane = threadIdx.x & 63;
    int wid = (blockIdx.x * 256 + threadIdx.x) >> 6;
    int fg = lane & 7;
    int n = wid * 8 + (lane >> 3);
    bool valid = (n < N);
    int nc = valid ? n : (N - 1);
    int srcbase = lane & 56;

    float4 xv = *(const float4*)&x[nc*4];
    float4 pb = *(const float4*)&proj_b[fg*4];
    float hold[4];
    {
        float pbv[4] = {pb.x, pb.y, pb.z, pb.w};
        #pragma unroll
        for (int j = 0; j < 4; ++j) {
            float a = pbv[j];
            a = fmaf(xv.x, proj_w[0*32 + fg*4 + j], a);
            a = fmaf(xv.y, proj_w[1*32 + fg*4 + j], a);
            a = fmaf(xv.z, proj_w[2*32 + fg*4 + j], a);
            a = fmaf(xv.w, proj_w[3*32 + fg*4 + j], a);
            hold[j] = fmaxf(a, 0.f);
        }
    }
    if (valid) {
        *(float4*)&h[n*32 + fg*4]   = make_float4(hold[0], hold[1], hold[2], hold[3]);
        *(float4*)&agg[n*32 + fg*4] = make_float4(0.f, 0.f, 0.f, 0.f);
    }

    float gacc[9][4];
    #pragma unroll
    for (int c = 0; c < 9; ++c)
        #pragma unroll
        for (int j = 0; j < 4; ++j) gacc[c][j] = 0.f;
    #pragma unroll
    for (int i = 0; i < 32; ++i) {
        float hv = __shfl(hold[i & 3], srcbase | (i >> 2), 64);
        #pragma unroll
        for (int c = 0; c < 9; ++c) {
            const float* Wc = (c < 8) ? (e2w + c*1024) : e2b;
            float4 w4 = *(const float4*)&Wc[i*32 + fg*4];
            gacc[c][0] = fmaf(hv, w4.x, gacc[c][0]);
            gacc[c][1] = fmaf(hv, w4.y, gacc[c][1]);
            gacc[c][2] = fmaf(hv, w4.z, gacc[c][2]);
            gacc[c][3] = fmaf(hv, w4.w, gacc[c][3]);
        }
    }
    if (valid) {
        #pragma unroll
        for (int c = 0; c < 9; ++c)
            *(float4*)&G[(size_t)n*288 + c*32 + fg*4] =
                make_float4(gacc[c][0], gacc[c][1], gacc[c][2], gacc[c][3]);
    }
}

// ---------------- fused iteration: conv-out -> GRU -> h; optional G recompute ----------------
__global__ __launch_bounds__(256) void k_iter(
    float* __restrict__ h, float* __restrict__ agg,
    const float* __restrict__ root_w, const float* __restrict__ conv_b,
    const float* __restrict__ WI, const float* __restrict__ WH, const float* __restrict__ BS,
    const float* __restrict__ e2w, const float* __restrict__ e2b,
    float* __restrict__ G, int N, int computeG)
{
    int lane = threadIdx.x & 63;
    int wid = (blockIdx.x * 256 + threadIdx.x) >> 6;
    int fg = lane & 7;
    int n = wid * 8 + (lane >> 3);
    bool valid = (n < N);
    int nc = valid ? n : (N - 1);
    int srcbase = lane & 56;

    float4 hv4 = *(const float4*)&h[nc*32 + fg*4];
    float hold[4] = {hv4.x, hv4.y, hv4.z, hv4.w};
    float4 av4 = *(const float4*)&agg[nc*32 + fg*4];
    float4 cb4 = *(const float4*)&conv_b[fg*4];
    float outv[4] = {av4.x + cb4.x, av4.y + cb4.y, av4.z + cb4.z, av4.w + cb4.w};
    float gh0[4] = {0.f,0.f,0.f,0.f};
    float gh1[4] = {0.f,0.f,0.f,0.f};
    float gh2[4];
    {
        float4 b3 = *(const float4*)&BS[96 + fg*4];
        gh2[0]=b3.x; gh2[1]=b3.y; gh2[2]=b3.z; gh2[3]=b3.w;
    }

    // phase 1: out_pre += h@root_w ; gh = h@WH (3 gates)
    #pragma unroll
    for (int i = 0; i < 32; ++i) {
        float hv = __shfl(hold[i & 3], srcbase | (i >> 2), 64);
        float4 w0 = *(const float4*)&root_w[i*32 + fg*4];
        float4 w1 = *(const float4*)&WH[0*1024 + i*32 + fg*4];
        float4 w2 = *(const float4*)&WH[1*1024 + i*32 + fg*4];
        float4 w3 = *(const float4*)&WH[2*1024 + i*32 + fg*4];
        outv[0]=fmaf(hv,w0.x,outv[0]); outv[1]=fmaf(hv,w0.y,outv[1]);
        outv[2]=fmaf(hv,w0.z,outv[2]); outv[3]=fmaf(hv,w0.w,outv[3]);
        gh0[0]=fmaf(hv,w1.x,gh0[0]); gh0[1]=fmaf(hv,w1.y,gh0[1]);
        gh0[2]=fmaf(hv,w1.z,gh0[2]); gh0[3]=fmaf(hv,w1.w,gh0[3]);
        gh1[0]=fmaf(hv,w2.x,gh1[0]); gh1[1]=fmaf(hv,w2.y,gh1[1]);
        gh1[2]=fmaf(hv,w2.z,gh1[2]); gh1[3]=fmaf(hv,w2.w,gh1[3]);
        gh2[0]=fmaf(hv,w3.x,gh2[0]); gh2[1]=fmaf(hv,w3.y,gh2[1]);
        gh2[2]=fmaf(hv,w3.z,gh2[2]); gh2[3]=fmaf(hv,w3.w,gh2[3]);
    }
    float outr[4];
    #pragma unroll
    for (int j = 0; j < 4; ++j) outr[j] = fmaxf(outv[j], 0.f);
    if (valid) *(float4*)&agg[n*32 + fg*4] = make_float4(0.f,0.f,0.f,0.f);

    // phase 2: gi = out@WI (3 gates)
    float gi0[4], gi1[4], gi2[4];
    {
        float4 b0 = *(const float4*)&BS[fg*4];
        float4 b1 = *(const float4*)&BS[32 + fg*4];
        float4 b2 = *(const float4*)&BS[64 + fg*4];
        gi0[0]=b0.x; gi0[1]=b0.y; gi0[2]=b0.z; gi0[3]=b0.w;
        gi1[0]=b1.x; gi1[1]=b1.y; gi1[2]=b1.z; gi1[3]=b1.w;
        gi2[0]=b2.x; gi2[1]=b2.y; gi2[2]=b2.z; gi2[3]=b2.w;
    }
    #pragma unroll
    for (int i = 0; i < 32; ++i) {
        float ov = __shfl(outr[i & 3], srcbase | (i >> 2), 64);
        float4 w1 = *(const float4*)&WI[0*1024 + i*32 + fg*4];
        float4 w2 = *(const float4*)&WI[1*1024 + i*32 + fg*4];
        float4 w3 = *(const float4*)&WI[2*1024 + i*32 + fg*4];
        gi0[0]=fmaf(ov,w1.x,gi0[0]); gi0[1]=fmaf(ov,w1.y,gi0[1]);
        gi0[2]=fmaf(ov,w1.z,gi0[2]); gi0[3]=fmaf(ov,w1.w,gi0[3]);
        gi1[0]=fmaf(ov,w2.x,gi1[0]); gi1[1]=fmaf(ov,w2.y,gi1[1]);
        gi1[2]=fmaf(ov,w2.z,gi1[2]); gi1[3]=fmaf(ov,w2.w,gi1[3]);
        gi2[0]=fmaf(ov,w3.x,gi2[0]); gi2[1]=fmaf(ov,w3.y,gi2[1]);
        gi2[2]=fmaf(ov,w3.z,gi2[2]); gi2[3]=fmaf(ov,w3.w,gi2[3]);
    }

    // elementwise GRU
    float hnew[4];
    #pragma unroll
    for (int j = 0; j < 4; ++j) {
        float r = sigmoidf_(gi0[j] + gh0[j]);
        float z = sigmoidf_(gi1[j] + gh1[j]);
        float nn = tanhf(gi2[j] + r * gh2[j]);
        hnew[j] = (1.f - z) * nn + z * hold[j];
    }
    if (valid) *(float4*)&h[n*32 + fg*4] = make_float4(hnew[0], hnew[1], hnew[2], hnew[3]);

    // phase 3: G = hnew @ W3 (9 chunks of 32 cols)
    if (computeG) {
        float gacc[9][4];
        #pragma unroll
        for (int c = 0; c < 9; ++c)
            #pragma unroll
            for (int j = 0; j < 4; ++j) gacc[c][j] = 0.f;
        #pragma unroll
        for (int i = 0; i < 32; ++i) {
            float hv = __shfl(hnew[i & 3], srcbase | (i >> 2), 64);
            #pragma unroll
            for (int c = 0; c < 9; ++c) {
                const float* Wc = (c < 8) ? (e2w + c*1024) : e2b;
                float4 w4 = *(const float4*)&Wc[i*32 + fg*4];
                gacc[c][0] = fmaf(hv, w4.x, gacc[c][0]);
                gacc[c][1] = fmaf(hv, w4.y, gacc[c][1]);
                gacc[c][2] = fmaf(hv, w4.z, gacc[c][2]);
                gacc[c][3] = fmaf(hv, w4.w, gacc[c][3]);
            }
        }
        if (valid) {
            #pragma unroll
            for (int c = 0; c < 9; ++c)
                *(float4*)&G[(size_t)n*288 + c*32 + fg*4] =
                    make_float4(gacc[c][0], gacc[c][1], gacc[c][2], gacc[c][3]);
        }
    }
}

// ---------------- edges: m[e,o] = sum_k t_k G[src,k,o] + G[src,8,o]; atomic agg[dst] ----------------
__global__ __launch_bounds__(256) void k_edge(
    const int* __restrict__ ei, const float* __restrict__ ea,
    const float* __restrict__ e1w, const float* __restrict__ e1b,
    const float* __restrict__ G, float* __restrict__ agg, int E)
{
    int tid = blockIdx.x * 256 + threadIdx.x;
    int e = tid >> 5;
    int o = tid & 31;
    if (e >= E) return;
    int src = ei[e];
    int dst = ei[E + e];
    float a = ea[e];
    const float* Gp = G + (size_t)src * 288;
    float m = Gp[8 * H + o];
    #pragma unroll
    for (int k = 0; k < 8; ++k) {
        float t = fmaxf(a * e1w[k] + e1b[k], 0.f);
        m += t * Gp[k * H + o];
    }
    atomicAdd(&agg[dst * H + o], m);
}

__device__ __forceinline__ unsigned int fenc(float f) {
    int i = __float_as_int(f);
    return (i >= 0) ? ((unsigned int)i | 0x80000000u) : ~(unsigned int)i;
}
__device__ __forceinline__ float fdec(unsigned int u) {
    int i = (u & 0x80000000u) ? (int)(u & 0x7FFFFFFFu) : (int)(~u);
    return __int_as_float(i);
}

// ---------------- readout pass1: e[n] = h[n]·q, segment max ----------------
__global__ __launch_bounds__(256) void k_pass1(
    const float* __restrict__ h, const int* __restrict__ batch,
    const float* __restrict__ qvec, float* __restrict__ ebuf,
    unsigned int* __restrict__ segmax, int N)
{
    int b = blockIdx.x / CHUNKS;
    int c = blockIdx.x % CHUNKS;
    int lo = 0, hi = N;
    while (lo < hi) { int mid = (lo + hi) >> 1; if (batch[mid] < b) lo = mid + 1; else hi = mid; }
    int s = lo;
    lo = 0; hi = N;
    while (lo < hi) { int mid = (lo + hi) >> 1; if (batch[mid] < b + 1) lo = mid + 1; else hi = mid; }
    int e = lo;
    int len = e - s;
    int per = (len + CHUNKS - 1) / CHUNKS;
    int n0 = s + c * per;
    int n1 = min(n0 + per, e);

    int tid = threadIdx.x;
    int ln = tid >> 5, o = tid & 31;
    float qv = qvec[o];
    float mloc = -INFINITY;
    for (int nn = n0 + ln; nn < n1; nn += 8) {
        float v = h[nn * H + o] * qv;
        #pragma unroll
        for (int m = 16; m >= 1; m >>= 1) v += __shfl_xor(v, m);
        if (o == 0) ebuf[nn] = v;
        mloc = fmaxf(mloc, v);
    }
    __shared__ float red[256];
    red[tid] = mloc;
    __syncthreads();
    for (int st = 128; st >= 1; st >>= 1) {
        if (tid < st) red[tid] = fmaxf(red[tid], red[tid + st]);
        __syncthreads();
    }
    if (tid == 0 && n0 < n1) atomicMax(&segmax[b], fenc(red[0]));
}

// ---------------- readout pass2: a = exp(e - emax); vsum += a*h; ssum += a ----------------
__global__ __launch_bounds__(256) void k_pass2(
    const float* __restrict__ h, const int* __restrict__ batch,
    const float* __restrict__ ebuf, const unsigned int* __restrict__ segmax,
    float* __restrict__ ssum, float* __restrict__ vsum, int N)
{
    int b = blockIdx.x / CHUNKS;
    int c = blockIdx.x % CHUNKS;
    int lo = 0, hi = N;
    while (lo < hi) { int mid = (lo + hi) >> 1; if (batch[mid] < b) lo = mid + 1; else hi = mid; }
    int s = lo;
    lo = 0; hi = N;
    while (lo < hi) { int mid = (lo + hi) >> 1; if (batch[mid] < b + 1) lo = mid + 1; else hi = mid; }
    int e = lo;
    int len = e - s;
    int per = (len + CHUNKS - 1) / CHUNKS;
    int n0 = s + c * per;
    int n1 = min(n0 + per, e);

    int tid = threadIdx.x;
    int ln = tid >> 5, o = tid & 31;
    float emax = fdec(segmax[b]);
    float vacc = 0.f, sacc = 0.f;
    for (int nn = n0 + ln; nn < n1; nn += 8) {
        float a = expf(ebuf[nn] - emax);
        vacc += a * h[nn * H + o];
        if (o == 0) sacc += a;
    }
    __shared__ float vsh[8][H];
    __shared__ float ssh[8];
    vsh[ln][o] = vacc;
    if (o == 0) ssh[ln] = sacc;
    __syncthreads();
    if (tid < H) {
        float v = 0.f;
        #pragma unroll
        for (int g = 0; g < 8; ++g) v += vsh[g][tid];
        atomicAdd(&vsum[b * H + tid], v);
    } else if (tid == H) {
        float stot = 0.f;
        #pragma unroll
        for (int g = 0; g < 8; ++g) stot += ssh[g];
        atomicAdd(&ssum[b], stot);
    }
}

// ---------------- final MLP on (16, 64) ----------------
__global__ __launch_bounds__(512) void k_mlp(
    const float* __restrict__ qvec, const float* __restrict__ ssum, const float* __restrict__ vsum,
    const float* __restrict__ f1w, const float* __restrict__ f1b,
    const float* __restrict__ f2w, const float* __restrict__ f2b,
    const float* __restrict__ f3w, const float* __restrict__ f3b,
    float* __restrict__ out)
{
    __shared__ float qsm[BSEG][2 * H];
    __shared__ float o1[BSEG][H];
    __shared__ float o2[BSEG][H];
    int tid = threadIdx.x;
    int b = tid >> 5, j = tid & 31;
    float st = ssum[b];
    qsm[b][j] = qvec[j];
    qsm[b][H + j] = (st > 0.f) ? vsum[b * H + j] / st : 0.f;
    __syncthreads();
    float acc = f1b[j];
    for (int i = 0; i < 2 * H; ++i) acc += qsm[b][i] * f1w[i * H + j];
    o1[b][j] = fmaxf(acc, 0.f);
    __syncthreads();
    acc = f2b[j];
    for (int i = 0; i < H; ++i) acc += o1[b][i] * f2w[i * H + j];
    o2[b][j] = fmaxf(acc, 0.f);
    __syncthreads();
    float v = o2[b][j] * f3w[j];
    #pragma unroll
    for (int m = 16; m >= 1; m >>= 1) v += __shfl_xor(v, m);
    if (j == 0) out[b] = v + f3b[0];
}

extern "C" void kernel_launch(void* const* d_in, const int* in_sizes, int n_in,
                              void* d_out, int out_size, void* d_ws, size_t ws_size,
                              hipStream_t stream)
{
    const float* x      = (const float*)d_in[0];
    const int*   ei     = (const int*)d_in[1];
    const float* ea     = (const float*)d_in[2];
    const int*   batch  = (const int*)d_in[3];
    const float* proj_w = (const float*)d_in[4];
    const float* proj_b = (const float*)d_in[5];
    const float* e1w    = (const float*)d_in[6];
    const float* e1b    = (const float*)d_in[7];
    const float* e2w    = (const float*)d_in[8];
    const float* e2b    = (const float*)d_in[9];
    const float* root_w = (const float*)d_in[10];
    const float* conv_b = (const float*)d_in[11];
    const float* gru_wi = (const float*)d_in[12];
    const float* gru_wh = (const float*)d_in[13];
    const float* gru_bi = (const float*)d_in[14];
    const float* gru_bh = (const float*)d_in[15];
    const float* lstm_bi = (const float*)d_in[18];
    const float* lstm_bh = (const float*)d_in[19];
    const float* f1w    = (const float*)d_in[20];
    const float* f1b    = (const float*)d_in[21];
    const float* f2w    = (const float*)d_in[22];
    const float* f2b    = (const float*)d_in[23];
    const float* f3w    = (const float*)d_in[24];
    const float* f3b    = (const float*)d_in[25];

    const int N = in_sizes[0] / 4;
    const int E = in_sizes[2];

    float* ws   = (float*)d_ws;
    float* h    = ws;                       // N*32
    float* G    = h + (size_t)N * H;        // N*288
    float* agg  = G + (size_t)N * 288;      // N*32
    float* ebuf = agg + (size_t)N * H;      // N
    float* qvec = ebuf + N;                 // 32
    unsigned int* segmax = (unsigned int*)(qvec + H);  // 16
    float* ssum = (float*)(segmax + BSEG);  // 16
    float* vsum = ssum + BSEG;              // 512
    float* WI   = vsum + BSEG * H;          // 3072
    float* WH   = WI + 3072;                // 3072
    float* BS   = WH + 3072;                // 128

    const int nwaves = (N + 7) / 8;
    const int nb = (nwaves * 64 + 255) / 256;
    const int eblocks = (E * 32 + 255) / 256;

    k_prep<<<1, 512, 0, stream>>>(gru_wi, gru_wh, gru_bi, gru_bh, lstm_bi, lstm_bh,
                                  WI, WH, BS, qvec, segmax, ssum, vsum);
    k_init<<<nb, 256, 0, stream>>>(x, proj_w, proj_b, e2w, e2b, h, G, agg, N);
    for (int it = 0; it < 3; ++it) {
        k_edge<<<eblocks, 256, 0, stream>>>(ei, ea, e1w, e1b, G, agg, E);
        k_iter<<<nb, 256, 0, stream>>>(h, agg, root_w, conv_b, WI, WH, BS,
                                       e2w, e2b, G, N, it < 2 ? 1 : 0);
    }
    k_pass1<<<BSEG * CHUNKS, 256, 0, stream>>>(h, batch, qvec, ebuf, segmax, N);
    k_pass2<<<BSEG * CHUNKS, 256, 0, stream>>>(h, batch, ebuf, segmax, ssum, vsum, N);
    k_mlp<<<1, 512, 0, stream>>>(qvec, ssum, vsum, f1w, f1b, f2w, f2b, f3w, f3b, (float*)d_out);
}

// Round 6
// 291.615 us; speedup vs baseline: 11.5470x; 4.0534x over previous
//
#include <hip/hip_runtime.h>
#include <math.h>

#define H 32
#define BSEG 16
#define CHUNKS 32

__device__ __forceinline__ float sigmoidf_(float x){ return 1.f/(1.f+expf(-x)); }

// ---------------- prep: transposed GRU weights, fused biases, qvec, zero accumulators ----------------
// WI[k*1024 + i*32 + o] = gru_wi[(k*32+o)*32 + i]
// WH[k*1024 + i*32 + o] = gru_wh[(k*32+o)*32 + i]
// BS[0..31]=bi0+bh0, [32..63]=bi1+bh1, [64..95]=bi2, [96..127]=bh2
__global__ __launch_bounds__(512) void k_prep(
    const float* __restrict__ gru_wi, const float* __restrict__ gru_wh,
    const float* __restrict__ gru_bi, const float* __restrict__ gru_bh,
    const float* __restrict__ lstm_bi, const float* __restrict__ lstm_bh,
    float* __restrict__ WI, float* __restrict__ WH, float* __restrict__ BS,
    float* __restrict__ qvec, unsigned int* __restrict__ segmax,
    float* __restrict__ ssum, float* __restrict__ vsum)
{
    int t = threadIdx.x;
    for (int idx = t; idx < 3072; idx += 512) {
        int k = idx >> 10, rem = idx & 1023, i = rem >> 5, o = rem & 31;
        WI[idx] = gru_wi[(k*32 + o)*32 + i];
        WH[idx] = gru_wh[(k*32 + o)*32 + i];
    }
    if (t < 32) {
        BS[t]      = gru_bi[t]      + gru_bh[t];
        BS[32 + t] = gru_bi[32 + t] + gru_bh[32 + t];
        BS[64 + t] = gru_bi[64 + t];
        BS[96 + t] = gru_bh[64 + t];
    }
    if (t < H) {
        float g0 = lstm_bi[t] + lstm_bh[t];
        float g2 = lstm_bi[2*H + t] + lstm_bh[2*H + t];
        float g3 = lstm_bi[3*H + t] + lstm_bh[3*H + t];
        float ig = sigmoidf_(g0);
        float gg = tanhf(g2);
        float og = sigmoidf_(g3);
        qvec[t] = og * tanhf(ig * gg);
    }
    for (int i = t; i < BSEG; i += 512) { segmax[i] = 0u; ssum[i] = 0.f; }
    for (int i = t; i < BSEG*H; i += 512) vsum[i] = 0.f;
}

// ---- K=32 pass accumulating TWO output matrices (bounded in-flight loads) ----
// lane = node8*8 + fg; xreg[j] holds X[node][fg*4+j]; output a/b[j] += sum_i X[i]*W[i][fg*4+j]
__device__ __forceinline__ void pass2mat(const float xreg[4], int srcbase, int fg,
                                         const float* __restrict__ W0,
                                         const float* __restrict__ W1,
                                         float a[4], float b[4])
{
    #pragma unroll 1
    for (int i4 = 0; i4 < 32; i4 += 4) {
        int src = srcbase | (i4 >> 2);
        float x0 = __shfl(xreg[0], src, 64);
        float x1 = __shfl(xreg[1], src, 64);
        float x2 = __shfl(xreg[2], src, 64);
        float x3 = __shfl(xreg[3], src, 64);
        float4 w00 = *(const float4*)&W0[(i4+0)*32 + fg*4];
        float4 w01 = *(const float4*)&W0[(i4+1)*32 + fg*4];
        float4 w02 = *(const float4*)&W0[(i4+2)*32 + fg*4];
        float4 w03 = *(const float4*)&W0[(i4+3)*32 + fg*4];
        float4 w10 = *(const float4*)&W1[(i4+0)*32 + fg*4];
        float4 w11 = *(const float4*)&W1[(i4+1)*32 + fg*4];
        float4 w12 = *(const float4*)&W1[(i4+2)*32 + fg*4];
        float4 w13 = *(const float4*)&W1[(i4+3)*32 + fg*4];
        a[0]=fmaf(x0,w00.x,a[0]); a[1]=fmaf(x0,w00.y,a[1]); a[2]=fmaf(x0,w00.z,a[2]); a[3]=fmaf(x0,w00.w,a[3]);
        a[0]=fmaf(x1,w01.x,a[0]); a[1]=fmaf(x1,w01.y,a[1]); a[2]=fmaf(x1,w01.z,a[2]); a[3]=fmaf(x1,w01.w,a[3]);
        a[0]=fmaf(x2,w02.x,a[0]); a[1]=fmaf(x2,w02.y,a[1]); a[2]=fmaf(x2,w02.z,a[2]); a[3]=fmaf(x2,w02.w,a[3]);
        a[0]=fmaf(x3,w03.x,a[0]); a[1]=fmaf(x3,w03.y,a[1]); a[2]=fmaf(x3,w03.z,a[2]); a[3]=fmaf(x3,w03.w,a[3]);
        b[0]=fmaf(x0,w10.x,b[0]); b[1]=fmaf(x0,w10.y,b[1]); b[2]=fmaf(x0,w10.z,b[2]); b[3]=fmaf(x0,w10.w,b[3]);
        b[0]=fmaf(x1,w11.x,b[0]); b[1]=fmaf(x1,w11.y,b[1]); b[2]=fmaf(x1,w11.z,b[2]); b[3]=fmaf(x1,w11.w,b[3]);
        b[0]=fmaf(x2,w12.x,b[0]); b[1]=fmaf(x2,w12.y,b[1]); b[2]=fmaf(x2,w12.z,b[2]); b[3]=fmaf(x2,w12.w,b[3]);
        b[0]=fmaf(x3,w13.x,b[0]); b[1]=fmaf(x3,w13.y,b[1]); b[2]=fmaf(x3,w13.z,b[2]); b[3]=fmaf(x3,w13.w,b[3]);
    }
}

// ---- K=32 pass, ONE output matrix ----
__device__ __forceinline__ void pass1mat(const float xreg[4], int srcbase, int fg,
                                         const float* __restrict__ W0, float a[4])
{
    #pragma unroll 1
    for (int i4 = 0; i4 < 32; i4 += 4) {
        int src = srcbase | (i4 >> 2);
        float x0 = __shfl(xreg[0], src, 64);
        float x1 = __shfl(xreg[1], src, 64);
        float x2 = __shfl(xreg[2], src, 64);
        float x3 = __shfl(xreg[3], src, 64);
        float4 w00 = *(const float4*)&W0[(i4+0)*32 + fg*4];
        float4 w01 = *(const float4*)&W0[(i4+1)*32 + fg*4];
        float4 w02 = *(const float4*)&W0[(i4+2)*32 + fg*4];
        float4 w03 = *(const float4*)&W0[(i4+3)*32 + fg*4];
        a[0]=fmaf(x0,w00.x,a[0]); a[1]=fmaf(x0,w00.y,a[1]); a[2]=fmaf(x0,w00.z,a[2]); a[3]=fmaf(x0,w00.w,a[3]);
        a[0]=fmaf(x1,w01.x,a[0]); a[1]=fmaf(x1,w01.y,a[1]); a[2]=fmaf(x1,w01.z,a[2]); a[3]=fmaf(x1,w01.w,a[3]);
        a[0]=fmaf(x2,w02.x,a[0]); a[1]=fmaf(x2,w02.y,a[1]); a[2]=fmaf(x2,w02.z,a[2]); a[3]=fmaf(x2,w02.w,a[3]);
        a[0]=fmaf(x3,w03.x,a[0]); a[1]=fmaf(x3,w03.y,a[1]); a[2]=fmaf(x3,w03.z,a[2]); a[3]=fmaf(x3,w03.w,a[3]);
    }
}

// ---- G recompute from x-regs: 9 chunks, chunk-outer (bounded registers) ----
__device__ __forceinline__ void computeG_(const float xreg[4], int srcbase, int fg,
                                          const float* __restrict__ e2w,
                                          const float* __restrict__ e2b,
                                          float* __restrict__ G, int n, bool valid)
{
    #pragma unroll 1
    for (int c = 0; c < 9; ++c) {
        const float* __restrict__ Wc = (c < 8) ? (e2w + c*1024) : e2b;
        float acc[4] = {0.f, 0.f, 0.f, 0.f};
        pass1mat(xreg, srcbase, fg, Wc, acc);
        if (valid)
            *(float4*)&G[(size_t)n*288 + c*32 + fg*4] =
                make_float4(acc[0], acc[1], acc[2], acc[3]);
    }
}

// ---------------- init: h = relu(x@proj_w+proj_b); G; agg = 0. 8 nodes/wave ----------------
__global__ __launch_bounds__(256, 4) void k_init(
    const float* __restrict__ x, const float* __restrict__ proj_w, const float* __restrict__ proj_b,
    const float* __restrict__ e2w, const float* __restrict__ e2b,
    float* __restrict__ h, float* __restrict__ G, float* __restrict__ agg, int N)
{
    int lane = threadIdx.x & 63;
    int wid = (blockIdx.x * 256 + threadIdx.x) >> 6;
    int fg = lane & 7;
    int n = wid * 8 + (lane >> 3);
    bool valid = (n < N);
    int nc = valid ? n : (N - 1);
    int srcbase = lane & 56;

    float4 xv = *(const float4*)&x[nc*4];
    float hold[4];
    {
        float4 pb = *(const float4*)&proj_b[fg*4];
        float pbv[4] = {pb.x, pb.y, pb.z, pb.w};
        #pragma unroll
        for (int j = 0; j < 4; ++j) {
            float a = pbv[j];
            a = fmaf(xv.x, proj_w[0*32 + fg*4 + j], a);
            a = fmaf(xv.y, proj_w[1*32 + fg*4 + j], a);
            a = fmaf(xv.z, proj_w[2*32 + fg*4 + j], a);
            a = fmaf(xv.w, proj_w[3*32 + fg*4 + j], a);
            hold[j] = fmaxf(a, 0.f);
        }
    }
    if (valid) {
        *(float4*)&h[n*32 + fg*4]   = make_float4(hold[0], hold[1], hold[2], hold[3]);
        *(float4*)&agg[n*32 + fg*4] = make_float4(0.f, 0.f, 0.f, 0.f);
    }
    computeG_(hold, srcbase, fg, e2w, e2b, G, n, valid);
}

// ---------------- fused iteration: conv-out -> GRU -> h; optional G recompute ----------------
__global__ __launch_bounds__(256, 4) void k_iter(
    float* __restrict__ h, float* __restrict__ agg,
    const float* __restrict__ root_w, const float* __restrict__ conv_b,
    const float* __restrict__ WI, const float* __restrict__ WH, const float* __restrict__ BS,
    const float* __restrict__ e2w, const float* __restrict__ e2b,
    float* __restrict__ G, int N, int computeG)
{
    int lane = threadIdx.x & 63;
    int wid = (blockIdx.x * 256 + threadIdx.x) >> 6;
    int fg = lane & 7;
    int n = wid * 8 + (lane >> 3);
    bool valid = (n < N);
    int nc = valid ? n : (N - 1);
    int srcbase = lane & 56;

    float4 hv4 = *(const float4*)&h[nc*32 + fg*4];
    float hold[4] = {hv4.x, hv4.y, hv4.z, hv4.w};

    // out_pre = agg + conv_b + h@root_w ; gh2 = bh2 + h@WH2
    float outv[4], gh2[4];
    {
        float4 av4 = *(const float4*)&agg[nc*32 + fg*4];
        float4 cb4 = *(const float4*)&conv_b[fg*4];
        outv[0]=av4.x+cb4.x; outv[1]=av4.y+cb4.y; outv[2]=av4.z+cb4.z; outv[3]=av4.w+cb4.w;
        float4 b3 = *(const float4*)&BS[96 + fg*4];
        gh2[0]=b3.x; gh2[1]=b3.y; gh2[2]=b3.z; gh2[3]=b3.w;
    }
    pass2mat(hold, srcbase, fg, root_w, WH + 2048, outv, gh2);

    // gh0 = h@WH0 ; gh1 = h@WH1
    float gh0[4] = {0.f,0.f,0.f,0.f};
    float gh1[4] = {0.f,0.f,0.f,0.f};
    pass2mat(hold, srcbase, fg, WH, WH + 1024, gh0, gh1);

    float outr[4];
    #pragma unroll
    for (int j = 0; j < 4; ++j) outr[j] = fmaxf(outv[j], 0.f);
    if (valid) *(float4*)&agg[n*32 + fg*4] = make_float4(0.f,0.f,0.f,0.f);

    // gi0/gi1 = out@WI0/WI1 (+bs0/bs1) ; gi2 = out@WI2 (+bi2)
    float gi0[4], gi1[4], gi2[4];
    {
        float4 b0 = *(const float4*)&BS[fg*4];
        float4 b1 = *(const float4*)&BS[32 + fg*4];
        float4 b2 = *(const float4*)&BS[64 + fg*4];
        gi0[0]=b0.x; gi0[1]=b0.y; gi0[2]=b0.z; gi0[3]=b0.w;
        gi1[0]=b1.x; gi1[1]=b1.y; gi1[2]=b1.z; gi1[3]=b1.w;
        gi2[0]=b2.x; gi2[1]=b2.y; gi2[2]=b2.z; gi2[3]=b2.w;
    }
    pass2mat(outr, srcbase, fg, WI, WI + 1024, gi0, gi1);
    pass1mat(outr, srcbase, fg, WI + 2048, gi2);

    // elementwise GRU
    float hnew[4];
    #pragma unroll
    for (int j = 0; j < 4; ++j) {
        float r = sigmoidf_(gi0[j] + gh0[j]);
        float z = sigmoidf_(gi1[j] + gh1[j]);
        float nn = tanhf(gi2[j] + r * gh2[j]);
        hnew[j] = (1.f - z) * nn + z * hold[j];
    }
    if (valid) *(float4*)&h[n*32 + fg*4] = make_float4(hnew[0], hnew[1], hnew[2], hnew[3]);

    if (computeG)
        computeG_(hnew, srcbase, fg, e2w, e2b, G, n, valid);
}

// ---------------- edges: m[e,o] = sum_k t_k G[src,k,o] + G[src,8,o]; atomic agg[dst] ----------------
__global__ __launch_bounds__(256) void k_edge(
    const int* __restrict__ ei, const float* __restrict__ ea,
    const float* __restrict__ e1w, const float* __restrict__ e1b,
    const float* __restrict__ G, float* __restrict__ agg, int E)
{
    int tid = blockIdx.x * 256 + threadIdx.x;
    int e = tid >> 5;
    int o = tid & 31;
    if (e >= E) return;
    int src = ei[e];
    int dst = ei[E + e];
    float a = ea[e];
    const float* Gp = G + (size_t)src * 288;
    float m = Gp[8 * H + o];
    #pragma unroll
    for (int k = 0; k < 8; ++k) {
        float t = fmaxf(a * e1w[k] + e1b[k], 0.f);
        m += t * Gp[k * H + o];
    }
    atomicAdd(&agg[dst * H + o], m);
}

__device__ __forceinline__ unsigned int fenc(float f) {
    int i = __float_as_int(f);
    return (i >= 0) ? ((unsigned int)i | 0x80000000u) : ~(unsigned int)i;
}
__device__ __forceinline__ float fdec(unsigned int u) {
    int i = (u & 0x80000000u) ? (int)(u & 0x7FFFFFFFu) : (int)(~u);
    return __int_as_float(i);
}

// ---------------- readout pass1: e[n] = h[n]·q, segment max ----------------
__global__ __launch_bounds__(256) void k_pass1(
    const float* __restrict__ h, const int* __restrict__ batch,
    const float* __restrict__ qvec, float* __restrict__ ebuf,
    unsigned int* __restrict__ segmax, int N)
{
    int b = blockIdx.x / CHUNKS;
    int c = blockIdx.x % CHUNKS;
    int lo = 0, hi = N;
    while (lo < hi) { int mid = (lo + hi) >> 1; if (batch[mid] < b) lo = mid + 1; else hi = mid; }
    int s = lo;
    lo = 0; hi = N;
    while (lo < hi) { int mid = (lo + hi) >> 1; if (batch[mid] < b + 1) lo = mid + 1; else hi = mid; }
    int e = lo;
    int len = e - s;
    int per = (len + CHUNKS - 1) / CHUNKS;
    int n0 = s + c * per;
    int n1 = min(n0 + per, e);

    int tid = threadIdx.x;
    int ln = tid >> 5, o = tid & 31;
    float qv = qvec[o];
    float mloc = -INFINITY;
    for (int nn = n0 + ln; nn < n1; nn += 8) {
        float v = h[nn * H + o] * qv;
        #pragma unroll
        for (int m = 16; m >= 1; m >>= 1) v += __shfl_xor(v, m);
        if (o == 0) ebuf[nn] = v;
        mloc = fmaxf(mloc, v);
    }
    __shared__ float red[256];
    red[tid] = mloc;
    __syncthreads();
    for (int st = 128; st >= 1; st >>= 1) {
        if (tid < st) red[tid] = fmaxf(red[tid], red[tid + st]);
        __syncthreads();
    }
    if (tid == 0 && n0 < n1) atomicMax(&segmax[b], fenc(red[0]));
}

// ---------------- readout pass2: a = exp(e - emax); vsum += a*h; ssum += a ----------------
__global__ __launch_bounds__(256) void k_pass2(
    const float* __restrict__ h, const int* __restrict__ batch,
    const float* __restrict__ ebuf, const unsigned int* __restrict__ segmax,
    float* __restrict__ ssum, float* __restrict__ vsum, int N)
{
    int b = blockIdx.x / CHUNKS;
    int c = blockIdx.x % CHUNKS;
    int lo = 0, hi = N;
    while (lo < hi) { int mid = (lo + hi) >> 1; if (batch[mid] < b) lo = mid + 1; else hi = mid; }
    int s = lo;
    lo = 0; hi = N;
    while (lo < hi) { int mid = (lo + hi) >> 1; if (batch[mid] < b + 1) lo = mid + 1; else hi = mid; }
    int e = lo;
    int len = e - s;
    int per = (len + CHUNKS - 1) / CHUNKS;
    int n0 = s + c * per;
    int n1 = min(n0 + per, e);

    int tid = threadIdx.x;
    int ln = tid >> 5, o = tid & 31;
    float emax = fdec(segmax[b]);
    float vacc = 0.f, sacc = 0.f;
    for (int nn = n0 + ln; nn < n1; nn += 8) {
        float a = expf(ebuf[nn] - emax);
        vacc += a * h[nn * H + o];
        if (o == 0) sacc += a;
    }
    __shared__ float vsh[8][H];
    __shared__ float ssh[8];
    vsh[ln][o] = vacc;
    if (o == 0) ssh[ln] = sacc;
    __syncthreads();
    if (tid < H) {
        float v = 0.f;
        #pragma unroll
        for (int g = 0; g < 8; ++g) v += vsh[g][tid];
        atomicAdd(&vsum[b * H + tid], v);
    } else if (tid == H) {
        float stot = 0.f;
        #pragma unroll
        for (int g = 0; g < 8; ++g) stot += ssh[g];
        atomicAdd(&ssum[b], stot);
    }
}

// ---------------- final MLP on (16, 64) ----------------
__global__ __launch_bounds__(512) void k_mlp(
    const float* __restrict__ qvec, const float* __restrict__ ssum, const float* __restrict__ vsum,
    const float* __restrict__ f1w, const float* __restrict__ f1b,
    const float* __restrict__ f2w, const float* __restrict__ f2b,
    const float* __restrict__ f3w, const float* __restrict__ f3b,
    float* __restrict__ out)
{
    __shared__ float qsm[BSEG][2 * H];
    __shared__ float o1[BSEG][H];
    __shared__ float o2[BSEG][H];
    int tid = threadIdx.x;
    int b = tid >> 5, j = tid & 31;
    float st = ssum[b];
    qsm[b][j] = qvec[j];
    qsm[b][H + j] = (st > 0.f) ? vsum[b * H + j] / st : 0.f;
    __syncthreads();
    float acc = f1b[j];
    for (int i = 0; i < 2 * H; ++i) acc += qsm[b][i] * f1w[i * H + j];
    o1[b][j] = fmaxf(acc, 0.f);
    __syncthreads();
    acc = f2b[j];
    for (int i = 0; i < H; ++i) acc += o1[b][i] * f2w[i * H + j];
    o2[b][j] = fmaxf(acc, 0.f);
    __syncthreads();
    float v = o2[b][j] * f3w[j];
    #pragma unroll
    for (int m = 16; m >= 1; m >>= 1) v += __shfl_xor(v, m);
    if (j == 0) out[b] = v + f3b[0];
}

extern "C" void kernel_launch(void* const* d_in, const int* in_sizes, int n_in,
                              void* d_out, int out_size, void* d_ws, size_t ws_size,
                              hipStream_t stream)
{
    const float* x      = (const float*)d_in[0];
    const int*   ei     = (const int*)d_in[1];
    const float* ea     = (const float*)d_in[2];
    const int*   batch  = (const int*)d_in[3];
    const float* proj_w = (const float*)d_in[4];
    const float* proj_b = (const float*)d_in[5];
    const float* e1w    = (const float*)d_in[6];
    const float* e1b    = (const float*)d_in[7];
    const float* e2w    = (const float*)d_in[8];
    const float* e2b    = (const float*)d_in[9];
    const float* root_w = (const float*)d_in[10];
    const float* conv_b = (const float*)d_in[11];
    const float* gru_wi = (const float*)d_in[12];
    const float* gru_wh = (const float*)d_in[13];
    const float* gru_bi = (const float*)d_in[14];
    const float* gru_bh = (const float*)d_in[15];
    const float* lstm_bi = (const float*)d_in[18];
    const float* lstm_bh = (const float*)d_in[19];
    const float* f1w    = (const float*)d_in[20];
    const float* f1b    = (const float*)d_in[21];
    const float* f2w    = (const float*)d_in[22];
    const float* f2b    = (const float*)d_in[23];
    const float* f3w    = (const float*)d_in[24];
    const float* f3b    = (const float*)d_in[25];

    const int N = in_sizes[0] / 4;
    const int E = in_sizes[2];

    float* ws   = (float*)d_ws;
    float* h    = ws;                       // N*32
    float* G    = h + (size_t)N * H;        // N*288
    float* agg  = G + (size_t)N * 288;      // N*32
    float* ebuf = agg + (size_t)N * H;      // N
    float* qvec = ebuf + N;                 // 32
    unsigned int* segmax = (unsigned int*)(qvec + H);  // 16
    float* ssum = (float*)(segmax + BSEG);  // 16
    float* vsum = ssum + BSEG;              // 512
    float* WI   = vsum + BSEG * H;          // 3072
    float* WH   = WI + 3072;                // 3072
    float* BS   = WH + 3072;                // 128

    const int nwaves = (N + 7) / 8;
    const int nb = (nwaves * 64 + 255) / 256;
    const int eblocks = (E * 32 + 255) / 256;

    k_prep<<<1, 512, 0, stream>>>(gru_wi, gru_wh, gru_bi, gru_bh, lstm_bi, lstm_bh,
                                  WI, WH, BS, qvec, segmax, ssum, vsum);
    k_init<<<nb, 256, 0, stream>>>(x, proj_w, proj_b, e2w, e2b, h, G, agg, N);
    for (int it = 0; it < 3; ++it) {
        k_edge<<<eblocks, 256, 0, stream>>>(ei, ea, e1w, e1b, G, agg, E);
        k_iter<<<nb, 256, 0, stream>>>(h, agg, root_w, conv_b, WI, WH, BS,
                                       e2w, e2b, G, N, it < 2 ? 1 : 0);
    }
    k_pass1<<<BSEG * CHUNKS, 256, 0, stream>>>(h, batch, qvec, ebuf, segmax, N);
    k_pass2<<<BSEG * CHUNKS, 256, 0, stream>>>(h, batch, ebuf, segmax, ssum, vsum, N);
    k_mlp<<<1, 512, 0, stream>>>(qvec, ssum, vsum, f1w, f1b, f2w, f2b, f3w, f3b, (float*)d_out);
}

// Round 7
// 221.319 us; speedup vs baseline: 15.2146x; 1.3176x over previous
//
#include <hip/hip_runtime.h>
#include <math.h>

#define H 32
#define BSEG 16
#define CHUNKS 32

__device__ __forceinline__ float sigmoidf_(float x){ return 1.f/(1.f+expf(-x)); }

// ---------------- prep: transposed GRU weights, fused biases, qvec, zero accumulators ----------------
// WI[k*1024 + i*32 + o] = gru_wi[(k*32+o)*32 + i]
// WH[k*1024 + i*32 + o] = gru_wh[(k*32+o)*32 + i]
// BS[0..31]=bi0+bh0, [32..63]=bi1+bh1, [64..95]=bi2, [96..127]=bh2
__global__ __launch_bounds__(512) void k_prep(
    const float* __restrict__ gru_wi, const float* __restrict__ gru_wh,
    const float* __restrict__ gru_bi, const float* __restrict__ gru_bh,
    const float* __restrict__ lstm_bi, const float* __restrict__ lstm_bh,
    float* __restrict__ WI, float* __restrict__ WH, float* __restrict__ BS,
    float* __restrict__ qvec, unsigned int* __restrict__ segmax,
    float* __restrict__ ssum, float* __restrict__ vsum)
{
    int t = threadIdx.x;
    for (int idx = t; idx < 3072; idx += 512) {
        int k = idx >> 10, rem = idx & 1023, i = rem >> 5, o = rem & 31;
        WI[idx] = gru_wi[(k*32 + o)*32 + i];
        WH[idx] = gru_wh[(k*32 + o)*32 + i];
    }
    if (t < 32) {
        BS[t]      = gru_bi[t]      + gru_bh[t];
        BS[32 + t] = gru_bi[32 + t] + gru_bh[32 + t];
        BS[64 + t] = gru_bi[64 + t];
        BS[96 + t] = gru_bh[64 + t];
    }
    if (t < H) {
        float g0 = lstm_bi[t] + lstm_bh[t];
        float g2 = lstm_bi[2*H + t] + lstm_bh[2*H + t];
        float g3 = lstm_bi[3*H + t] + lstm_bh[3*H + t];
        float ig = sigmoidf_(g0);
        float gg = tanhf(g2);
        float og = sigmoidf_(g3);
        qvec[t] = og * tanhf(ig * gg);
    }
    for (int i = t; i < BSEG; i += 512) { segmax[i] = 0u; ssum[i] = 0.f; }
    for (int i = t; i < BSEG*H; i += 512) vsum[i] = 0.f;
}

// ---- LDS-based K=32 passes. x row broadcast across the 8 fg-lanes of a node;
// ---- weight reads broadcast across the 8 node-lanes of an fg. Bank-conflict-free.
__device__ __forceinline__ void pass2_lds(const float* sm, int xb, int w0, int w1, int fg4,
                                          float a[4], float b[4])
{
    #pragma unroll 2
    for (int i4 = 0; i4 < 32; i4 += 4) {
        float4 xv  = *(const float4*)&sm[xb + i4];
        float4 w00 = *(const float4*)&sm[w0 + (i4+0)*32 + fg4];
        float4 w01 = *(const float4*)&sm[w0 + (i4+1)*32 + fg4];
        float4 w02 = *(const float4*)&sm[w0 + (i4+2)*32 + fg4];
        float4 w03 = *(const float4*)&sm[w0 + (i4+3)*32 + fg4];
        float4 w10 = *(const float4*)&sm[w1 + (i4+0)*32 + fg4];
        float4 w11 = *(const float4*)&sm[w1 + (i4+1)*32 + fg4];
        float4 w12 = *(const float4*)&sm[w1 + (i4+2)*32 + fg4];
        float4 w13 = *(const float4*)&sm[w1 + (i4+3)*32 + fg4];
        a[0]=fmaf(xv.x,w00.x,a[0]); a[1]=fmaf(xv.x,w00.y,a[1]); a[2]=fmaf(xv.x,w00.z,a[2]); a[3]=fmaf(xv.x,w00.w,a[3]);
        a[0]=fmaf(xv.y,w01.x,a[0]); a[1]=fmaf(xv.y,w01.y,a[1]); a[2]=fmaf(xv.y,w01.z,a[2]); a[3]=fmaf(xv.y,w01.w,a[3]);
        a[0]=fmaf(xv.z,w02.x,a[0]); a[1]=fmaf(xv.z,w02.y,a[1]); a[2]=fmaf(xv.z,w02.z,a[2]); a[3]=fmaf(xv.z,w02.w,a[3]);
        a[0]=fmaf(xv.w,w03.x,a[0]); a[1]=fmaf(xv.w,w03.y,a[1]); a[2]=fmaf(xv.w,w03.z,a[2]); a[3]=fmaf(xv.w,w03.w,a[3]);
        b[0]=fmaf(xv.x,w10.x,b[0]); b[1]=fmaf(xv.x,w10.y,b[1]); b[2]=fmaf(xv.x,w10.z,b[2]); b[3]=fmaf(xv.x,w10.w,b[3]);
        b[0]=fmaf(xv.y,w11.x,b[0]); b[1]=fmaf(xv.y,w11.y,b[1]); b[2]=fmaf(xv.y,w11.z,b[2]); b[3]=fmaf(xv.y,w11.w,b[3]);
        b[0]=fmaf(xv.z,w12.x,b[0]); b[1]=fmaf(xv.z,w12.y,b[1]); b[2]=fmaf(xv.z,w12.z,b[2]); b[3]=fmaf(xv.z,w12.w,b[3]);
        b[0]=fmaf(xv.w,w13.x,b[0]); b[1]=fmaf(xv.w,w13.y,b[1]); b[2]=fmaf(xv.w,w13.z,b[2]); b[3]=fmaf(xv.w,w13.w,b[3]);
    }
}

__device__ __forceinline__ void pass1_lds(const float* sm, int xb, int w0, int fg4, float a[4])
{
    #pragma unroll 2
    for (int i4 = 0; i4 < 32; i4 += 4) {
        float4 xv  = *(const float4*)&sm[xb + i4];
        float4 w00 = *(const float4*)&sm[w0 + (i4+0)*32 + fg4];
        float4 w01 = *(const float4*)&sm[w0 + (i4+1)*32 + fg4];
        float4 w02 = *(const float4*)&sm[w0 + (i4+2)*32 + fg4];
        float4 w03 = *(const float4*)&sm[w0 + (i4+3)*32 + fg4];
        a[0]=fmaf(xv.x,w00.x,a[0]); a[1]=fmaf(xv.x,w00.y,a[1]); a[2]=fmaf(xv.x,w00.z,a[2]); a[3]=fmaf(xv.x,w00.w,a[3]);
        a[0]=fmaf(xv.y,w01.x,a[0]); a[1]=fmaf(xv.y,w01.y,a[1]); a[2]=fmaf(xv.y,w01.z,a[2]); a[3]=fmaf(xv.y,w01.w,a[3]);
        a[0]=fmaf(xv.z,w02.x,a[0]); a[1]=fmaf(xv.z,w02.y,a[1]); a[2]=fmaf(xv.z,w02.z,a[2]); a[3]=fmaf(xv.z,w02.w,a[3]);
        a[0]=fmaf(xv.w,w03.x,a[0]); a[1]=fmaf(xv.w,w03.y,a[1]); a[2]=fmaf(xv.w,w03.z,a[2]); a[3]=fmaf(xv.w,w03.w,a[3]);
    }
}

// ---------------- proj: h = relu(x @ proj_w + proj_b); agg = 0. One node per lane. ----------------
__global__ __launch_bounds__(256) void k_proj(
    const float* __restrict__ x, const float* __restrict__ proj_w, const float* __restrict__ proj_b,
    float* __restrict__ h, float* __restrict__ agg, int N)
{
    int n = blockIdx.x * 256 + threadIdx.x;
    if (n >= N) return;
    float4 xv = *(const float4*)&x[n * 4];
    #pragma unroll
    for (int q = 0; q < 8; ++q) {
        float r_[4];
        #pragma unroll
        for (int j = 0; j < 4; ++j) {
            int o = q*4 + j;
            float a = proj_b[o];
            a = fmaf(xv.x, proj_w[0*32 + o], a);
            a = fmaf(xv.y, proj_w[1*32 + o], a);
            a = fmaf(xv.z, proj_w[2*32 + o], a);
            a = fmaf(xv.w, proj_w[3*32 + o], a);
            r_[j] = fmaxf(a, 0.f);
        }
        *(float4*)&h[n*32 + q*4]   = make_float4(r_[0], r_[1], r_[2], r_[3]);
        *(float4*)&agg[n*32 + q*4] = make_float4(0.f, 0.f, 0.f, 0.f);
    }
}

// ---------------- G: 3 chunks per block (blockIdx.y), weights in LDS, 8 nodes/wave ----------------
#define XG 3072
__global__ __launch_bounds__(256, 2) void k_G(
    const float* __restrict__ h, const float* __restrict__ e2w, const float* __restrict__ e2b,
    float* __restrict__ G, int N)
{
    __shared__ float sm[XG + 4*288];
    int tid = threadIdx.x;
    int cy = blockIdx.y;
    {
        float4* s4 = (float4*)sm;
        for (int i = tid; i < 768; i += 256) {
            int c = cy*3 + (i >> 8);
            const float4* src = (c < 8) ? (const float4*)(e2w + (size_t)c*1024)
                                        : (const float4*)e2b;
            s4[i] = src[i & 255];
        }
    }
    __syncthreads();

    int lane = tid & 63;
    int w = tid >> 6;
    int fg = lane & 7, fg4 = fg*4;
    int nw = lane >> 3;
    int n = (blockIdx.x * 4 + w) * 8 + nw;
    bool valid = (n < N);
    int nc = valid ? n : (N - 1);
    int xb = XG + w*288 + nw*36;

    float4 hv4 = *(const float4*)&h[nc*32 + fg4];
    *(float4*)&sm[xb + fg4] = hv4;        // wave-local write; lockstep ordering

    #pragma unroll 1
    for (int cc = 0; cc < 3; ++cc) {
        float acc[4] = {0.f, 0.f, 0.f, 0.f};
        pass1_lds(sm, xb, cc*1024, fg4, acc);
        if (valid)
            *(float4*)&G[(size_t)n*288 + (cy*3+cc)*32 + fg4] =
                make_float4(acc[0], acc[1], acc[2], acc[3]);
    }
}

// ---------------- GRU node update: weights + x rows in LDS, 8 nodes/wave ----------------
// LDS: ROOT[0,1024) WH[1024,4096) WI[4096,7168) X[7168,+4*288)
#define XU 7168
__global__ __launch_bounds__(256, 2) void k_gru(
    float* __restrict__ h, float* __restrict__ agg,
    const float* __restrict__ root_w, const float* __restrict__ conv_b,
    const float* __restrict__ WI, const float* __restrict__ WH, const float* __restrict__ BS,
    int N)
{
    __shared__ float sm[XU + 4*288];
    int tid = threadIdx.x;
    {
        float4* s4 = (float4*)sm;
        const float4* r4  = (const float4*)root_w;
        const float4* wh4 = (const float4*)WH;
        const float4* wi4 = (const float4*)WI;
        for (int i = tid; i < 256; i += 256) s4[i] = r4[i];
        for (int i = tid; i < 768; i += 256) s4[256  + i] = wh4[i];
        for (int i = tid; i < 768; i += 256) s4[1024 + i] = wi4[i];
    }
    __syncthreads();

    int lane = tid & 63;
    int w = tid >> 6;
    int fg = lane & 7, fg4 = fg*4;
    int nw = lane >> 3;
    int n = (blockIdx.x * 4 + w) * 8 + nw;
    bool valid = (n < N);
    int nc = valid ? n : (N - 1);
    int xb = XU + w*288 + nw*36;

    float4 hv4 = *(const float4*)&h[nc*32 + fg4];
    float hold[4] = {hv4.x, hv4.y, hv4.z, hv4.w};
    *(float4*)&sm[xb + fg4] = hv4;        // publish h row (wave-local)

    // out_pre = agg + conv_b + h@root_w ; gh2 = bh2 + h@WH2
    float outv[4], gh2[4];
    {
        float4 av4 = *(const float4*)&agg[nc*32 + fg4];
        float4 cb4 = *(const float4*)&conv_b[fg4];
        outv[0]=av4.x+cb4.x; outv[1]=av4.y+cb4.y; outv[2]=av4.z+cb4.z; outv[3]=av4.w+cb4.w;
        float4 b3 = *(const float4*)&BS[96 + fg4];
        gh2[0]=b3.x; gh2[1]=b3.y; gh2[2]=b3.z; gh2[3]=b3.w;
    }
    pass2_lds(sm, xb, 0, 1024 + 2048, fg4, outv, gh2);

    // gh0 = h@WH0 ; gh1 = h@WH1
    float gh0[4] = {0.f,0.f,0.f,0.f};
    float gh1[4] = {0.f,0.f,0.f,0.f};
    pass2_lds(sm, xb, 1024, 2048, fg4, gh0, gh1);

    float outr[4];
    #pragma unroll
    for (int j = 0; j < 4; ++j) outr[j] = fmaxf(outv[j], 0.f);
    if (valid) *(float4*)&agg[n*32 + fg4] = make_float4(0.f,0.f,0.f,0.f);

    // publish out row (overwrite x; all h-row reads completed in program order)
    *(float4*)&sm[xb + fg4] = make_float4(outr[0], outr[1], outr[2], outr[3]);

    float gi0[4], gi1[4], gi2[4];
    {
        float4 b0 = *(const float4*)&BS[fg4];
        float4 b1 = *(const float4*)&BS[32 + fg4];
        float4 b2 = *(const float4*)&BS[64 + fg4];
        gi0[0]=b0.x; gi0[1]=b0.y; gi0[2]=b0.z; gi0[3]=b0.w;
        gi1[0]=b1.x; gi1[1]=b1.y; gi1[2]=b1.z; gi1[3]=b1.w;
        gi2[0]=b2.x; gi2[1]=b2.y; gi2[2]=b2.z; gi2[3]=b2.w;
    }
    pass2_lds(sm, xb, 4096, 5120, fg4, gi0, gi1);
    pass1_lds(sm, xb, 6144, fg4, gi2);

    float hnew[4];
    #pragma unroll
    for (int j = 0; j < 4; ++j) {
        float r = sigmoidf_(gi0[j] + gh0[j]);
        float z = sigmoidf_(gi1[j] + gh1[j]);
        float nn = tanhf(gi2[j] + r * gh2[j]);
        hnew[j] = (1.f - z) * nn + z * hold[j];
    }
    if (valid) *(float4*)&h[n*32 + fg4] = make_float4(hnew[0], hnew[1], hnew[2], hnew[3]);
}

// ---------------- edges: m[e,o] = sum_k t_k G[src,k,o] + G[src,8,o]; atomic agg[dst] ----------------
__global__ __launch_bounds__(256) void k_edge(
    const int* __restrict__ ei, const float* __restrict__ ea,
    const float* __restrict__ e1w, const float* __restrict__ e1b,
    const float* __restrict__ G, float* __restrict__ agg, int E)
{
    int tid = blockIdx.x * 256 + threadIdx.x;
    int e = tid >> 5;
    int o = tid & 31;
    if (e >= E) return;
    int src = ei[e];
    int dst = ei[E + e];
    float a = ea[e];
    const float* Gp = G + (size_t)src * 288;
    float m = Gp[8 * H + o];
    #pragma unroll
    for (int k = 0; k < 8; ++k) {
        float t = fmaxf(a * e1w[k] + e1b[k], 0.f);
        m += t * Gp[k * H + o];
    }
    atomicAdd(&agg[dst * H + o], m);
}

__device__ __forceinline__ unsigned int fenc(float f) {
    int i = __float_as_int(f);
    return (i >= 0) ? ((unsigned int)i | 0x80000000u) : ~(unsigned int)i;
}
__device__ __forceinline__ float fdec(unsigned int u) {
    int i = (u & 0x80000000u) ? (int)(u & 0x7FFFFFFFu) : (int)(~u);
    return __int_as_float(i);
}

// ---------------- readout pass1: e[n] = h[n]·q, segment max ----------------
__global__ __launch_bounds__(256) void k_pass1(
    const float* __restrict__ h, const int* __restrict__ batch,
    const float* __restrict__ qvec, float* __restrict__ ebuf,
    unsigned int* __restrict__ segmax, int N)
{
    int b = blockIdx.x / CHUNKS;
    int c = blockIdx.x % CHUNKS;
    int lo = 0, hi = N;
    while (lo < hi) { int mid = (lo + hi) >> 1; if (batch[mid] < b) lo = mid + 1; else hi = mid; }
    int s = lo;
    lo = 0; hi = N;
    while (lo < hi) { int mid = (lo + hi) >> 1; if (batch[mid] < b + 1) lo = mid + 1; else hi = mid; }
    int e = lo;
    int len = e - s;
    int per = (len + CHUNKS - 1) / CHUNKS;
    int n0 = s + c * per;
    int n1 = min(n0 + per, e);

    int tid = threadIdx.x;
    int ln = tid >> 5, o = tid & 31;
    float qv = qvec[o];
    float mloc = -INFINITY;
    for (int nn = n0 + ln; nn < n1; nn += 8) {
        float v = h[nn * H + o] * qv;
        #pragma unroll
        for (int m = 16; m >= 1; m >>= 1) v += __shfl_xor(v, m);
        if (o == 0) ebuf[nn] = v;
        mloc = fmaxf(mloc, v);
    }
    __shared__ float red[256];
    red[tid] = mloc;
    __syncthreads();
    for (int st = 128; st >= 1; st >>= 1) {
        if (tid < st) red[tid] = fmaxf(red[tid], red[tid + st]);
        __syncthreads();
    }
    if (tid == 0 && n0 < n1) atomicMax(&segmax[b], fenc(red[0]));
}

// ---------------- readout pass2: a = exp(e - emax); vsum += a*h; ssum += a ----------------
__global__ __launch_bounds__(256) void k_pass2(
    const float* __restrict__ h, const int* __restrict__ batch,
    const float* __restrict__ ebuf, const unsigned int* __restrict__ segmax,
    float* __restrict__ ssum, float* __restrict__ vsum, int N)
{
    int b = blockIdx.x / CHUNKS;
    int c = blockIdx.x % CHUNKS;
    int lo = 0, hi = N;
    while (lo < hi) { int mid = (lo + hi) >> 1; if (batch[mid] < b) lo = mid + 1; else hi = mid; }
    int s = lo;
    lo = 0; hi = N;
    while (lo < hi) { int mid = (lo + hi) >> 1; if (batch[mid] < b + 1) lo = mid + 1; else hi = mid; }
    int e = lo;
    int len = e - s;
    int per = (len + CHUNKS - 1) / CHUNKS;
    int n0 = s + c * per;
    int n1 = min(n0 + per, e);

    int tid = threadIdx.x;
    int ln = tid >> 5, o = tid & 31;
    float emax = fdec(segmax[b]);
    float vacc = 0.f, sacc = 0.f;
    for (int nn = n0 + ln; nn < n1; nn += 8) {
        float a = expf(ebuf[nn] - emax);
        vacc += a * h[nn * H + o];
        if (o == 0) sacc += a;
    }
    __shared__ float vsh[8][H];
    __shared__ float ssh[8];
    vsh[ln][o] = vacc;
    if (o == 0) ssh[ln] = sacc;
    __syncthreads();
    if (tid < H) {
        float v = 0.f;
        #pragma unroll
        for (int g = 0; g < 8; ++g) v += vsh[g][tid];
        atomicAdd(&vsum[b * H + tid], v);
    } else if (tid == H) {
        float stot = 0.f;
        #pragma unroll
        for (int g = 0; g < 8; ++g) stot += ssh[g];
        atomicAdd(&ssum[b], stot);
    }
}

// ---------------- final MLP on (16, 64) ----------------
__global__ __launch_bounds__(512) void k_mlp(
    const float* __restrict__ qvec, const float* __restrict__ ssum, const float* __restrict__ vsum,
    const float* __restrict__ f1w, const float* __restrict__ f1b,
    const float* __restrict__ f2w, const float* __restrict__ f2b,
    const float* __restrict__ f3w, const float* __restrict__ f3b,
    float* __restrict__ out)
{
    __shared__ float qsm[BSEG][2 * H];
    __shared__ float o1[BSEG][H];
    __shared__ float o2[BSEG][H];
    int tid = threadIdx.x;
    int b = tid >> 5, j = tid & 31;
    float st = ssum[b];
    qsm[b][j] = qvec[j];
    qsm[b][H + j] = (st > 0.f) ? vsum[b * H + j] / st : 0.f;
    __syncthreads();
    float acc = f1b[j];
    for (int i = 0; i < 2 * H; ++i) acc += qsm[b][i] * f1w[i * H + j];
    o1[b][j] = fmaxf(acc, 0.f);
    __syncthreads();
    acc = f2b[j];
    for (int i = 0; i < H; ++i) acc += o1[b][i] * f2w[i * H + j];
    o2[b][j] = fmaxf(acc, 0.f);
    __syncthreads();
    float v = o2[b][j] * f3w[j];
    #pragma unroll
    for (int m = 16; m >= 1; m >>= 1) v += __shfl_xor(v, m);
    if (j == 0) out[b] = v + f3b[0];
}

extern "C" void kernel_launch(void* const* d_in, const int* in_sizes, int n_in,
                              void* d_out, int out_size, void* d_ws, size_t ws_size,
                              hipStream_t stream)
{
    const float* x      = (const float*)d_in[0];
    const int*   ei     = (const int*)d_in[1];
    const float* ea     = (const float*)d_in[2];
    const int*   batch  = (const int*)d_in[3];
    const float* proj_w = (const float*)d_in[4];
    const float* proj_b = (const float*)d_in[5];
    const float* e1w    = (const float*)d_in[6];
    const float* e1b    = (const float*)d_in[7];
    const float* e2w    = (const float*)d_in[8];
    const float* e2b    = (const float*)d_in[9];
    const float* root_w = (const float*)d_in[10];
    const float* conv_b = (const float*)d_in[11];
    const float* gru_wi = (const float*)d_in[12];
    const float* gru_wh = (const float*)d_in[13];
    const float* gru_bi = (const float*)d_in[14];
    const float* gru_bh = (const float*)d_in[15];
    const float* lstm_bi = (const float*)d_in[18];
    const float* lstm_bh = (const float*)d_in[19];
    const float* f1w    = (const float*)d_in[20];
    const float* f1b    = (const float*)d_in[21];
    const float* f2w    = (const float*)d_in[22];
    const float* f2b    = (const float*)d_in[23];
    const float* f3w    = (const float*)d_in[24];
    const float* f3b    = (const float*)d_in[25];

    const int N = in_sizes[0] / 4;
    const int E = in_sizes[2];

    float* ws   = (float*)d_ws;
    float* h    = ws;                       // N*32
    float* G    = h + (size_t)N * H;        // N*288
    float* agg  = G + (size_t)N * 288;      // N*32
    float* ebuf = agg + (size_t)N * H;      // N
    float* qvec = ebuf + N;                 // 32
    unsigned int* segmax = (unsigned int*)(qvec + H);  // 16
    float* ssum = (float*)(segmax + BSEG);  // 16
    float* vsum = ssum + BSEG;              // 512
    float* WI   = vsum + BSEG * H;          // 3072
    float* WH   = WI + 3072;                // 3072
    float* BS   = WH + 3072;                // 128

    const int nwaves = (N + 7) / 8;         // 8 nodes per wave
    const int nb4 = (nwaves + 3) / 4;       // 4 waves per block
    const int pblocks = (N + 255) / 256;
    const int eblocks = (E * 32 + 255) / 256;

    k_prep<<<1, 512, 0, stream>>>(gru_wi, gru_wh, gru_bi, gru_bh, lstm_bi, lstm_bh,
                                  WI, WH, BS, qvec, segmax, ssum, vsum);
    k_proj<<<pblocks, 256, 0, stream>>>(x, proj_w, proj_b, h, agg, N);
    k_G<<<dim3(nb4, 3), 256, 0, stream>>>(h, e2w, e2b, G, N);
    for (int it = 0; it < 3; ++it) {
        k_edge<<<eblocks, 256, 0, stream>>>(ei, ea, e1w, e1b, G, agg, E);
        k_gru<<<nb4, 256, 0, stream>>>(h, agg, root_w, conv_b, WI, WH, BS, N);
        if (it < 2) k_G<<<dim3(nb4, 3), 256, 0, stream>>>(h, e2w, e2b, G, N);
    }
    k_pass1<<<BSEG * CHUNKS, 256, 0, stream>>>(h, batch, qvec, ebuf, segmax, N);
    k_pass2<<<BSEG * CHUNKS, 256, 0, stream>>>(h, batch, ebuf, segmax, ssum, vsum, N);
    k_mlp<<<1, 512, 0, stream>>>(qvec, ssum, vsum, f1w, f1b, f2w, f2b, f3w, f3b, (float*)d_out);
}